// Round 10
// baseline (397.702 us; speedup 1.0000x reference)
//
#include <hip/hip_runtime.h>
#include <math.h>

#define DIM 64
#define CBSH 9                 // coarse bucket: 512 dst nodes
#define CBSZ (1 << CBSH)
#define CHUNK 4096             // edges per partition block

__device__ __forceinline__ float leaky(float e) { return e > 0.f ? e : 0.2f * e; }

// ---------------- CSR build ----------------
// P1: per-block histogram over coarse buckets + merged global degree count.
__global__ __launch_bounds__(256) void k_part_hist(
        const int* __restrict__ ei, int* __restrict__ deg,
        int* __restrict__ hist2d, int E, int NPB, int NCB) {
    __shared__ int hist[256];
    int blk = blockIdx.x;
    int base = blk * CHUNK;
    int ecnt = min(CHUNK, E - base);
    for (int i = threadIdx.x; i < 256; i += 256) hist[i] = 0;
    __syncthreads();
    for (int i = threadIdx.x; i < ecnt; i += 256) {
        int d = ei[E + base + i];
        atomicAdd(&hist[d >> CBSH], 1);   // LDS
        atomicAdd(&deg[d], 1);            // global (deg memset to 0 beforehand)
    }
    __syncthreads();
    for (int cb = threadIdx.x; cb < NCB; cb += 256)
        hist2d[cb * NPB + blk] = hist[cb];
}

// deg[i]+1 accounts for the self loop (deg array holds edge-only counts).
__global__ void k_scan_block(const int* __restrict__ deg, int* excl, int* bsum, int n) {
    __shared__ int tmp[256];
    int i = blockIdx.x * 256 + threadIdx.x;
    int v = (i < n) ? deg[i] + 1 : 0;
    tmp[threadIdx.x] = v;
    __syncthreads();
    for (int off = 1; off < 256; off <<= 1) {
        int t = (threadIdx.x >= off) ? tmp[threadIdx.x - off] : 0;
        __syncthreads();
        tmp[threadIdx.x] += t;
        __syncthreads();
    }
    if (i < n) excl[i] = tmp[threadIdx.x] - v;   // exclusive within block
    if (threadIdx.x == 255) bsum[blockIdx.x] = tmp[255];
}

__global__ void k_scan_partials(int* bsum, int nb) {   // nb <= 512
    __shared__ int tmp[512];
    int t = threadIdx.x;
    int v = (t < nb) ? bsum[t] : 0;
    tmp[t] = v;
    __syncthreads();
    for (int off = 1; off < 512; off <<= 1) {
        int u = (t >= off) ? tmp[t - off] : 0;
        __syncthreads();
        tmp[t] += u;
        __syncthreads();
    }
    if (t < nb) bsum[t] = tmp[t] - v;  // exclusive block offsets
}

__global__ void k_scan_finish(int* excl, const int* __restrict__ bsum, int n, int total) {
    int i = blockIdx.x * blockDim.x + threadIdx.x;
    if (i < n) excl[i] += bsum[i >> 8];
    if (i == 0) excl[n] = total;
}

// P2: per coarse bucket, exclusive-scan the per-block counts -> run bases.
__global__ __launch_bounds__(512) void k_part_scan(
        const int* __restrict__ row_ptr, int* __restrict__ hist2d, int NPB) {
    __shared__ int tmp[512];
    int cb = blockIdx.x;
    int t = threadIdx.x;
    int v = (t < NPB) ? hist2d[cb * NPB + t] : 0;
    tmp[t] = v;
    __syncthreads();
    for (int off = 1; off < 512; off <<= 1) {
        int u = (t >= off) ? tmp[t - off] : 0;
        __syncthreads();
        tmp[t] += u;
        __syncthreads();
    }
    int d0 = cb << CBSH;
    int base = row_ptr[d0] - d0;
    if (t < NPB) hist2d[cb * NPB + t] = base + tmp[t] - v;
}

// P3: write edges into this block's private contiguous runs (one run per
// coarse bucket) -> single-XCD temporally-tight writes, full-line combining.
__global__ __launch_bounds__(256) void k_part_scatter(
        const int* __restrict__ ei, const int* __restrict__ hist2d,
        int2* __restrict__ part, int E, int NPB, int NCB) {
    __shared__ int gb[256];
    __shared__ int cnt[256];
    int blk = blockIdx.x;
    int base = blk * CHUNK;
    int ecnt = min(CHUNK, E - base);
    for (int i = threadIdx.x; i < NCB; i += 256) {
        gb[i] = hist2d[i * NPB + blk];
        cnt[i] = 0;
    }
    __syncthreads();
    for (int i = threadIdx.x; i < ecnt; i += 256) {
        int s = ei[base + i];
        int d = ei[E + base + i];
        int cb = d >> CBSH;
        int off = atomicAdd(&cnt[cb], 1);  // LDS ticket within run
        part[gb[cb] + off] = make_int2(s, d);
    }
}

// phase D: one block per coarse bucket; LDS cursors; csr writes land in a
// ~35KB L2-resident window -> dense line fills.
__global__ __launch_bounds__(256) void k_bucket_scatter(
        const int* __restrict__ row_ptr, const int2* __restrict__ part,
        int* __restrict__ csr, int n) {
    __shared__ int lcur[CBSZ];
    int d0 = blockIdx.x << CBSH;
    int nb = min(CBSZ, n - d0);
    for (int j = threadIdx.x; j < nb; j += 256) {
        int node = d0 + j;
        int slot = row_ptr[node];
        csr[slot] = node;     // self loop at slot 0
        lcur[j] = slot + 1;
    }
    __syncthreads();
    int pbeg = row_ptr[d0] - d0;
    int pend = row_ptr[d0 + nb] - (d0 + nb);
    for (int p = pbeg + (int)threadIdx.x; p < pend; p += 256) {
        int2 e = part[p];
        int slot = atomicAdd(&lcur[e.y - d0], 1);
        csr[slot] = e.x;
    }
}

// ---------------- per-layer: K-tiled LDS GEMM + attention projections ----------------
template <int FIN>
__global__ __launch_bounds__(256, 4) void k_gemm_al(
        const float* __restrict__ x, int do_relu,
        const float* __restrict__ W,
        const float* __restrict__ as_, const float* __restrict__ ad_,
        float* __restrict__ h, float* __restrict__ als, float* __restrict__ ald,
        int n) {
    constexpr int KT = 64;
    constexpr int BM = 64;
    __shared__ float ws[KT * 64];        // [k][col]
    __shared__ float xs[BM * (KT + 1)];  // [row][k], stride 65

    const int tid = threadIdx.x;
    const int row0 = blockIdx.x * BM;
    const int rt = tid >> 4, ct = tid & 15;
    const int r0 = rt * 4, c0 = ct * 4;

    float acc[4][4];
#pragma unroll
    for (int i = 0; i < 4; ++i)
#pragma unroll
        for (int j = 0; j < 4; ++j) acc[i][j] = 0.f;

    for (int kt = 0; kt < FIN; kt += KT) {
#pragma unroll
        for (int p = 0; p < KT * 16 / 256; ++p) {
            int i = tid + p * 256;
            *reinterpret_cast<float4*>(&ws[i * 4]) =
                *reinterpret_cast<const float4*>(&W[kt * 64 + i * 4]);
        }
#pragma unroll
        for (int p = 0; p < BM * (KT / 4) / 256; ++p) {
            int i = tid + p * 256;
            int r = i >> 4;          // 16 quads per row
            int kq = i & 15;
            int grow = row0 + r;
            float4 v = make_float4(0.f, 0.f, 0.f, 0.f);
            if (grow < n)
                v = *reinterpret_cast<const float4*>(&x[(size_t)grow * FIN + kt + kq * 4]);
            if (do_relu) {
                v.x = fmaxf(v.x, 0.f); v.y = fmaxf(v.y, 0.f);
                v.z = fmaxf(v.z, 0.f); v.w = fmaxf(v.w, 0.f);
            }
            float* dst = &xs[r * (KT + 1) + kq * 4];
            dst[0] = v.x; dst[1] = v.y; dst[2] = v.z; dst[3] = v.w;
        }
        __syncthreads();

#pragma unroll 4
        for (int k = 0; k < KT; ++k) {
            float4 wv = *reinterpret_cast<const float4*>(&ws[k * 64 + c0]);
            float xv0 = xs[(r0 + 0) * (KT + 1) + k];
            float xv1 = xs[(r0 + 1) * (KT + 1) + k];
            float xv2 = xs[(r0 + 2) * (KT + 1) + k];
            float xv3 = xs[(r0 + 3) * (KT + 1) + k];
            acc[0][0] = fmaf(xv0, wv.x, acc[0][0]);
            acc[0][1] = fmaf(xv0, wv.y, acc[0][1]);
            acc[0][2] = fmaf(xv0, wv.z, acc[0][2]);
            acc[0][3] = fmaf(xv0, wv.w, acc[0][3]);
            acc[1][0] = fmaf(xv1, wv.x, acc[1][0]);
            acc[1][1] = fmaf(xv1, wv.y, acc[1][1]);
            acc[1][2] = fmaf(xv1, wv.z, acc[1][2]);
            acc[1][3] = fmaf(xv1, wv.w, acc[1][3]);
            acc[2][0] = fmaf(xv2, wv.x, acc[2][0]);
            acc[2][1] = fmaf(xv2, wv.y, acc[2][1]);
            acc[2][2] = fmaf(xv2, wv.z, acc[2][2]);
            acc[2][3] = fmaf(xv2, wv.w, acc[2][3]);
            acc[3][0] = fmaf(xv3, wv.x, acc[3][0]);
            acc[3][1] = fmaf(xv3, wv.y, acc[3][1]);
            acc[3][2] = fmaf(xv3, wv.z, acc[3][2]);
            acc[3][3] = fmaf(xv3, wv.w, acc[3][3]);
        }
        __syncthreads();
    }

    float4 asv = *reinterpret_cast<const float4*>(&as_[c0]);
    float4 adv = *reinterpret_cast<const float4*>(&ad_[c0]);
#pragma unroll
    for (int i = 0; i < 4; ++i) {
        int grow = row0 + r0 + i;
        if (grow < n) {
            *reinterpret_cast<float4*>(&h[(size_t)grow * 64 + c0]) =
                make_float4(acc[i][0], acc[i][1], acc[i][2], acc[i][3]);
        }
        float ps = acc[i][0] * asv.x + acc[i][1] * asv.y +
                   acc[i][2] * asv.z + acc[i][3] * asv.w;
        float pd = acc[i][0] * adv.x + acc[i][1] * adv.y +
                   acc[i][2] * adv.z + acc[i][3] * adv.w;
#pragma unroll
        for (int off = 1; off < 16; off <<= 1) {
            ps += __shfl_xor(ps, off);
            pd += __shfl_xor(pd, off);
        }
        if (ct == 0 && grow < n) { als[grow] = ps; ald[grow] = pd; }
    }
}

// ---------------- per-layer: fused logits + exact softmax + aggregation ----------------
// wave per destination node. Softmax phase: lanes compute logits+weights in
// parallel (1 exp/edge), shfl_xor max+sum. Gather phase: lane-group g=lane>>4
// handles row j+g, quad q=lane&15 covers dims 4q..4q+3 -> each float4 load
// instruction fetches 4 rows (1KB/wave), 2 substeps = 8 rows in flight.
// Epilogue: shfl_xor(32,16) cross-group reduce, 16-lane float4 store.
__global__ __launch_bounds__(256) void k_node_aggr(
        const int* __restrict__ row_ptr, const int* __restrict__ csr,
        const float* __restrict__ als, const float* __restrict__ ald,
        const float* __restrict__ h, const float* __restrict__ bias,
        float* __restrict__ out, int n) {
    int wid = threadIdx.x >> 6, lane = threadIdx.x & 63;
    int node = blockIdx.x * 4 + wid;
    if (node >= n) return;
    int beg = row_ptr[node];
    int deg = row_ptr[node + 1] - beg;
    float adv = ald[node];
    const int g = lane >> 4;   // row group
    const int q = lane & 15;   // quad within row
    float m = -INFINITY, ssum = 0.f;
    float4 acc = make_float4(0.f, 0.f, 0.f, 0.f);
    for (int c0 = 0; c0 < deg; c0 += 64) {
        int cn = min(64, deg - c0);
        int s_l = 0;
        float e_l = -INFINITY;
        if (lane < cn) {
            s_l = csr[beg + c0 + lane];
            e_l = leaky(als[s_l] + adv);
        }
        // chunk max
        float cm = e_l;
#pragma unroll
        for (int off = 32; off; off >>= 1) cm = fmaxf(cm, __shfl_xor(cm, off));
        float mnew = fmaxf(m, cm);
        float sc = __expf(m - mnew);   // first chunk: exp(-inf)=0
        // lane-parallel weights: ONE exp per edge; w=0 (s=0) for pad lanes
        float w_l = (lane < cn) ? __expf(e_l - mnew) : 0.f;
        float cs = w_l;
#pragma unroll
        for (int off = 32; off; off >>= 1) cs += __shfl_xor(cs, off);
        ssum = ssum * sc + cs;
        acc.x *= sc; acc.y *= sc; acc.z *= sc; acc.w *= sc;
        m = mnew;
        // gather: 8 rows per iteration via two 4-row float4 substeps.
        // j <= 56 so j+4+g <= 63: shfl indices never wrap; pad lanes have w=0.
        int cn8 = (cn + 7) & ~7;
        for (int j = 0; j < cn8; j += 8) {
            int   sa = __shfl(s_l, j + g);
            float wa = __shfl(w_l, j + g);
            int   sb = __shfl(s_l, j + 4 + g);
            float wb = __shfl(w_l, j + 4 + g);
            float4 ha = *reinterpret_cast<const float4*>(&h[(size_t)sa * DIM + q * 4]);
            float4 hb = *reinterpret_cast<const float4*>(&h[(size_t)sb * DIM + q * 4]);
            acc.x = fmaf(wa, ha.x, acc.x);
            acc.y = fmaf(wa, ha.y, acc.y);
            acc.z = fmaf(wa, ha.z, acc.z);
            acc.w = fmaf(wa, ha.w, acc.w);
            acc.x = fmaf(wb, hb.x, acc.x);
            acc.y = fmaf(wb, hb.y, acc.y);
            acc.z = fmaf(wb, hb.z, acc.z);
            acc.w = fmaf(wb, hb.w, acc.w);
        }
    }
    // cross-group reduce: lanes {q, q+16, q+32, q+48} hold partials of dims 4q..4q+3
#pragma unroll
    for (int off = 32; off >= 16; off >>= 1) {
        acc.x += __shfl_xor(acc.x, off);
        acc.y += __shfl_xor(acc.y, off);
        acc.z += __shfl_xor(acc.z, off);
        acc.w += __shfl_xor(acc.w, off);
    }
    if (lane < 16) {
        float inv = 1.f / ssum;
        float4 bv = *reinterpret_cast<const float4*>(&bias[q * 4]);
        float4 o;
        o.x = acc.x * inv + bv.x;
        o.y = acc.y * inv + bv.y;
        o.z = acc.z * inv + bv.z;
        o.w = acc.w * inv + bv.w;
        *reinterpret_cast<float4*>(&out[(size_t)node * DIM + q * 4]) = o;
    }
}

extern "C" void kernel_launch(void* const* d_in, const int* in_sizes, int n_in,
                              void* d_out, int out_size, void* d_ws, size_t ws_size,
                              hipStream_t stream) {
    const float* x = (const float*)d_in[0];
    const int* ei = (const int*)d_in[1];   // harness converts integer inputs to int32
    const int n = out_size / DIM;          // 100000
    const int E = in_sizes[1] / 2;         // 1600000
    const int total_edges = E + n;
    const int NCB = (n + CBSZ - 1) >> CBSH;      // 196 coarse buckets (<=256)
    const int NPB = (E + CHUNK - 1) / CHUNK;     // 391 partition blocks (<=512)

    const float *W[3], *as_[3], *ad_[3], *b[3];
    for (int l = 0; l < 3; ++l) {
        W[l]  = (const float*)d_in[2 + 4 * l];
        as_[l] = (const float*)d_in[3 + 4 * l];
        ad_[l] = (const float*)d_in[4 + 4 * l];
        b[l]  = (const float*)d_in[5 + 4 * l];
    }

    // workspace carve (256B aligned). Inter-layer activations live in d_out.
    char* ws = (char*)d_ws;
    size_t off = 0;
    auto alloc = [&](size_t bytes) {
        void* p = ws + off;
        off = (off + bytes + 255) & ~(size_t)255;
        return p;
    };
    int* deg      = (int*)alloc((size_t)n * 4);
    int* row_ptr  = (int*)alloc((size_t)(n + 1) * 4);
    int* bsum     = (int*)alloc(512 * 4);
    int* hist2d   = (int*)alloc((size_t)NCB * NPB * 4);
    int* csr      = (int*)alloc((size_t)total_edges * 4);
    int2* part    = (int2*)alloc((size_t)E * 8);
    float* h      = (float*)alloc((size_t)n * DIM * 4);
    float* als    = (float*)alloc((size_t)n * 4);
    float* ald    = (float*)alloc((size_t)n * 4);
    float* buf    = (float*)d_out;         // inter-layer activations

    const int nbn = (n + 255) / 256;       // 391 (<=512 for scan_partials)

    // ---- CSR build (once; shared by all 3 layers) ----
    hipMemsetAsync(deg, 0, (size_t)n * 4, stream);
    k_part_hist<<<NPB, 256, 0, stream>>>(ei, deg, hist2d, E, NPB, NCB);
    k_scan_block<<<nbn, 256, 0, stream>>>(deg, row_ptr, bsum, n);
    k_scan_partials<<<1, 512, 0, stream>>>(bsum, nbn);
    k_scan_finish<<<nbn, 256, 0, stream>>>(row_ptr, bsum, n, total_edges);
    k_part_scan<<<NCB, 512, 0, stream>>>(row_ptr, hist2d, NPB);
    k_part_scatter<<<NPB, 256, 0, stream>>>(ei, hist2d, part, E, NPB, NCB);
    k_bucket_scatter<<<NCB, 256, 0, stream>>>(row_ptr, part, csr, n);

    // ---- 3 GAT layers ----
    const int aggr_blocks = (n + 3) / 4;   // 4 waves (nodes) per 256-thread block
    const int gemm_blocks = (n + 63) / 64;
    const float* xin = x;
    for (int l = 0; l < 3; ++l) {
        if (l == 0) {
            k_gemm_al<128><<<gemm_blocks, 256, 0, stream>>>(
                xin, 0, W[l], as_[l], ad_[l], h, als, ald, n);
        } else {
            k_gemm_al<64><<<gemm_blocks, 256, 0, stream>>>(
                xin, 1, W[l], as_[l], ad_[l], h, als, ald, n);
        }
        float* dst = (l == 2) ? (float*)d_out : buf;
        k_node_aggr<<<aggr_blocks, 256, 0, stream>>>(row_ptr, csr, als, ald, h, b[l], dst, n);
        xin = buf;
    }
}

// Round 11
// 338.349 us; speedup vs baseline: 1.1754x; 1.1754x over previous
//
#include <hip/hip_runtime.h>
#include <hip/hip_fp16.h>
#include <math.h>

#define DIM 64
#define CBSH 9                 // coarse bucket: 512 dst nodes
#define CBSZ (1 << CBSH)
#define CHUNK 4096             // edges per partition block

__device__ __forceinline__ float leaky(float e) { return e > 0.f ? e : 0.2f * e; }

// ---------------- CSR build ----------------
// P1: per-block histogram over coarse buckets + merged global degree count.
__global__ __launch_bounds__(256) void k_part_hist(
        const int* __restrict__ ei, int* __restrict__ deg,
        int* __restrict__ hist2d, int E, int NPB, int NCB) {
    __shared__ int hist[256];
    int blk = blockIdx.x;
    int base = blk * CHUNK;
    int ecnt = min(CHUNK, E - base);
    for (int i = threadIdx.x; i < 256; i += 256) hist[i] = 0;
    __syncthreads();
    for (int i = threadIdx.x; i < ecnt; i += 256) {
        int d = ei[E + base + i];
        atomicAdd(&hist[d >> CBSH], 1);   // LDS
        atomicAdd(&deg[d], 1);            // global (deg memset to 0 beforehand)
    }
    __syncthreads();
    for (int cb = threadIdx.x; cb < NCB; cb += 256)
        hist2d[cb * NPB + blk] = hist[cb];
}

// deg[i]+1 accounts for the self loop (deg array holds edge-only counts).
__global__ void k_scan_block(const int* __restrict__ deg, int* excl, int* bsum, int n) {
    __shared__ int tmp[256];
    int i = blockIdx.x * 256 + threadIdx.x;
    int v = (i < n) ? deg[i] + 1 : 0;
    tmp[threadIdx.x] = v;
    __syncthreads();
    for (int off = 1; off < 256; off <<= 1) {
        int t = (threadIdx.x >= off) ? tmp[threadIdx.x - off] : 0;
        __syncthreads();
        tmp[threadIdx.x] += t;
        __syncthreads();
    }
    if (i < n) excl[i] = tmp[threadIdx.x] - v;   // exclusive within block
    if (threadIdx.x == 255) bsum[blockIdx.x] = tmp[255];
}

__global__ void k_scan_partials(int* bsum, int nb) {   // nb <= 512
    __shared__ int tmp[512];
    int t = threadIdx.x;
    int v = (t < nb) ? bsum[t] : 0;
    tmp[t] = v;
    __syncthreads();
    for (int off = 1; off < 512; off <<= 1) {
        int u = (t >= off) ? tmp[t - off] : 0;
        __syncthreads();
        tmp[t] += u;
        __syncthreads();
    }
    if (t < nb) bsum[t] = tmp[t] - v;  // exclusive block offsets
}

__global__ void k_scan_finish(int* excl, const int* __restrict__ bsum, int n, int total) {
    int i = blockIdx.x * blockDim.x + threadIdx.x;
    if (i < n) excl[i] += bsum[i >> 8];
    if (i == 0) excl[n] = total;
}

// P2: per coarse bucket, exclusive-scan the per-block counts -> run bases.
__global__ __launch_bounds__(512) void k_part_scan(
        const int* __restrict__ row_ptr, int* __restrict__ hist2d, int NPB) {
    __shared__ int tmp[512];
    int cb = blockIdx.x;
    int t = threadIdx.x;
    int v = (t < NPB) ? hist2d[cb * NPB + t] : 0;
    tmp[t] = v;
    __syncthreads();
    for (int off = 1; off < 512; off <<= 1) {
        int u = (t >= off) ? tmp[t - off] : 0;
        __syncthreads();
        tmp[t] += u;
        __syncthreads();
    }
    int d0 = cb << CBSH;
    int base = row_ptr[d0] - d0;
    if (t < NPB) hist2d[cb * NPB + t] = base + tmp[t] - v;
}

// P3: write edges into this block's private contiguous runs (one run per
// coarse bucket) -> single-XCD temporally-tight writes, full-line combining.
__global__ __launch_bounds__(256) void k_part_scatter(
        const int* __restrict__ ei, const int* __restrict__ hist2d,
        int2* __restrict__ part, int E, int NPB, int NCB) {
    __shared__ int gb[256];
    __shared__ int cnt[256];
    int blk = blockIdx.x;
    int base = blk * CHUNK;
    int ecnt = min(CHUNK, E - base);
    for (int i = threadIdx.x; i < NCB; i += 256) {
        gb[i] = hist2d[i * NPB + blk];
        cnt[i] = 0;
    }
    __syncthreads();
    for (int i = threadIdx.x; i < ecnt; i += 256) {
        int s = ei[base + i];
        int d = ei[E + base + i];
        int cb = d >> CBSH;
        int off = atomicAdd(&cnt[cb], 1);  // LDS ticket within run
        part[gb[cb] + off] = make_int2(s, d);
    }
}

// phase D: one block per coarse bucket; LDS cursors; csr writes land in a
// ~35KB L2-resident window -> dense line fills.
__global__ __launch_bounds__(256) void k_bucket_scatter(
        const int* __restrict__ row_ptr, const int2* __restrict__ part,
        int* __restrict__ csr, int n) {
    __shared__ int lcur[CBSZ];
    int d0 = blockIdx.x << CBSH;
    int nb = min(CBSZ, n - d0);
    for (int j = threadIdx.x; j < nb; j += 256) {
        int node = d0 + j;
        int slot = row_ptr[node];
        csr[slot] = node;     // self loop at slot 0
        lcur[j] = slot + 1;
    }
    __syncthreads();
    int pbeg = row_ptr[d0] - d0;
    int pend = row_ptr[d0 + nb] - (d0 + nb);
    for (int p = pbeg + (int)threadIdx.x; p < pend; p += 256) {
        int2 e = part[p];
        int slot = atomicAdd(&lcur[e.y - d0], 1);
        csr[slot] = e.x;
    }
}

// ---------------- per-layer: K-tiled LDS GEMM + attention projections ----------------
// h stored as fp16 (message payload only; als/ald/softmax stay fp32).
template <int FIN>
__global__ __launch_bounds__(256, 4) void k_gemm_al(
        const float* __restrict__ x, int do_relu,
        const float* __restrict__ W,
        const float* __restrict__ as_, const float* __restrict__ ad_,
        __half* __restrict__ h, float* __restrict__ als, float* __restrict__ ald,
        int n) {
    constexpr int KT = 64;
    constexpr int BM = 64;
    __shared__ float ws[KT * 64];        // [k][col]
    __shared__ float xs[BM * (KT + 1)];  // [row][k], stride 65

    const int tid = threadIdx.x;
    const int row0 = blockIdx.x * BM;
    const int rt = tid >> 4, ct = tid & 15;
    const int r0 = rt * 4, c0 = ct * 4;

    float acc[4][4];
#pragma unroll
    for (int i = 0; i < 4; ++i)
#pragma unroll
        for (int j = 0; j < 4; ++j) acc[i][j] = 0.f;

    for (int kt = 0; kt < FIN; kt += KT) {
#pragma unroll
        for (int p = 0; p < KT * 16 / 256; ++p) {
            int i = tid + p * 256;
            *reinterpret_cast<float4*>(&ws[i * 4]) =
                *reinterpret_cast<const float4*>(&W[kt * 64 + i * 4]);
        }
#pragma unroll
        for (int p = 0; p < BM * (KT / 4) / 256; ++p) {
            int i = tid + p * 256;
            int r = i >> 4;          // 16 quads per row
            int kq = i & 15;
            int grow = row0 + r;
            float4 v = make_float4(0.f, 0.f, 0.f, 0.f);
            if (grow < n)
                v = *reinterpret_cast<const float4*>(&x[(size_t)grow * FIN + kt + kq * 4]);
            if (do_relu) {
                v.x = fmaxf(v.x, 0.f); v.y = fmaxf(v.y, 0.f);
                v.z = fmaxf(v.z, 0.f); v.w = fmaxf(v.w, 0.f);
            }
            float* dst = &xs[r * (KT + 1) + kq * 4];
            dst[0] = v.x; dst[1] = v.y; dst[2] = v.z; dst[3] = v.w;
        }
        __syncthreads();

#pragma unroll 4
        for (int k = 0; k < KT; ++k) {
            float4 wv = *reinterpret_cast<const float4*>(&ws[k * 64 + c0]);
            float xv0 = xs[(r0 + 0) * (KT + 1) + k];
            float xv1 = xs[(r0 + 1) * (KT + 1) + k];
            float xv2 = xs[(r0 + 2) * (KT + 1) + k];
            float xv3 = xs[(r0 + 3) * (KT + 1) + k];
            acc[0][0] = fmaf(xv0, wv.x, acc[0][0]);
            acc[0][1] = fmaf(xv0, wv.y, acc[0][1]);
            acc[0][2] = fmaf(xv0, wv.z, acc[0][2]);
            acc[0][3] = fmaf(xv0, wv.w, acc[0][3]);
            acc[1][0] = fmaf(xv1, wv.x, acc[1][0]);
            acc[1][1] = fmaf(xv1, wv.y, acc[1][1]);
            acc[1][2] = fmaf(xv1, wv.z, acc[1][2]);
            acc[1][3] = fmaf(xv1, wv.w, acc[1][3]);
            acc[2][0] = fmaf(xv2, wv.x, acc[2][0]);
            acc[2][1] = fmaf(xv2, wv.y, acc[2][1]);
            acc[2][2] = fmaf(xv2, wv.z, acc[2][2]);
            acc[2][3] = fmaf(xv2, wv.w, acc[2][3]);
            acc[3][0] = fmaf(xv3, wv.x, acc[3][0]);
            acc[3][1] = fmaf(xv3, wv.y, acc[3][1]);
            acc[3][2] = fmaf(xv3, wv.z, acc[3][2]);
            acc[3][3] = fmaf(xv3, wv.w, acc[3][3]);
        }
        __syncthreads();
    }

    float4 asv = *reinterpret_cast<const float4*>(&as_[c0]);
    float4 adv = *reinterpret_cast<const float4*>(&ad_[c0]);
#pragma unroll
    for (int i = 0; i < 4; ++i) {
        int grow = row0 + r0 + i;
        if (grow < n) {
            __half2 p0 = __floats2half2_rn(acc[i][0], acc[i][1]);
            __half2 p1 = __floats2half2_rn(acc[i][2], acc[i][3]);
            uint2 pk = make_uint2(*reinterpret_cast<unsigned*>(&p0),
                                  *reinterpret_cast<unsigned*>(&p1));
            *reinterpret_cast<uint2*>(&h[(size_t)grow * 64 + c0]) = pk;  // 8B aligned
        }
        float ps = acc[i][0] * asv.x + acc[i][1] * asv.y +
                   acc[i][2] * asv.z + acc[i][3] * asv.w;
        float pd = acc[i][0] * adv.x + acc[i][1] * adv.y +
                   acc[i][2] * adv.z + acc[i][3] * adv.w;
#pragma unroll
        for (int off = 1; off < 16; off <<= 1) {
            ps += __shfl_xor(ps, off);
            pd += __shfl_xor(pd, off);
        }
        if (ct == 0 && grow < n) { als[grow] = ps; ald[grow] = pd; }
    }
}

// ---------------- per-layer: fused logits + exact softmax + aggregation ----------------
// wave per destination node. Softmax: lane-parallel logits+weights (1 exp/edge),
// shfl_xor max+sum. Gather: lanes pair rows (g=lane>>5), each lane loads __half2
// (dims 2q,2q+1) -> 2 rows per load instruction, 8 rows in flight, half the bytes
// of fp32. Epilogue: shfl_xor(32) cross-pair reduce, 32-lane float2 store.
__global__ __launch_bounds__(256) void k_node_aggr(
        const int* __restrict__ row_ptr, const int* __restrict__ csr,
        const float* __restrict__ als, const float* __restrict__ ald,
        const __half* __restrict__ h, const float* __restrict__ bias,
        float* __restrict__ out, int n) {
    int wid = threadIdx.x >> 6, lane = threadIdx.x & 63;
    int node = blockIdx.x * 4 + wid;
    if (node >= n) return;
    int beg = row_ptr[node];
    int deg = row_ptr[node + 1] - beg;
    float adv = ald[node];
    const int g = lane >> 5;   // row within pair
    const int q = lane & 31;   // dim-pair index (dims 2q, 2q+1)
    float m = -INFINITY, ssum = 0.f;
    float accx = 0.f, accy = 0.f;
    for (int c0 = 0; c0 < deg; c0 += 64) {
        int cn = min(64, deg - c0);
        int s_l = 0;
        float e_l = -INFINITY;
        if (lane < cn) {
            s_l = csr[beg + c0 + lane];
            e_l = leaky(als[s_l] + adv);
        }
        // chunk max
        float cm = e_l;
#pragma unroll
        for (int off = 32; off; off >>= 1) cm = fmaxf(cm, __shfl_xor(cm, off));
        float mnew = fmaxf(m, cm);
        float sc = __expf(m - mnew);   // first chunk: exp(-inf)=0
        // lane-parallel weights: ONE exp per edge; w=0 (s=0) for pad lanes
        float w_l = (lane < cn) ? __expf(e_l - mnew) : 0.f;
        float cs = w_l;
#pragma unroll
        for (int off = 32; off; off >>= 1) cs += __shfl_xor(cs, off);
        ssum = ssum * sc + cs;
        accx *= sc; accy *= sc;
        m = mnew;
        // gather: 8 rows per iteration (4 substeps x 2 rows). Pad lanes w=0.
        int cn8 = (cn + 7) & ~7;
        for (int j = 0; j < cn8; j += 8) {
            int   s0 = __shfl(s_l, j + g),     s1 = __shfl(s_l, j + 2 + g);
            int   s2 = __shfl(s_l, j + 4 + g), s3 = __shfl(s_l, j + 6 + g);
            float w0 = __shfl(w_l, j + g),     w1 = __shfl(w_l, j + 2 + g);
            float w2 = __shfl(w_l, j + 4 + g), w3 = __shfl(w_l, j + 6 + g);
            __half2 a0 = *reinterpret_cast<const __half2*>(&h[(size_t)s0 * DIM + 2 * q]);
            __half2 a1 = *reinterpret_cast<const __half2*>(&h[(size_t)s1 * DIM + 2 * q]);
            __half2 a2 = *reinterpret_cast<const __half2*>(&h[(size_t)s2 * DIM + 2 * q]);
            __half2 a3 = *reinterpret_cast<const __half2*>(&h[(size_t)s3 * DIM + 2 * q]);
            float2 f0 = __half22float2(a0);
            float2 f1 = __half22float2(a1);
            float2 f2 = __half22float2(a2);
            float2 f3 = __half22float2(a3);
            accx = fmaf(w0, f0.x, accx); accy = fmaf(w0, f0.y, accy);
            accx = fmaf(w1, f1.x, accx); accy = fmaf(w1, f1.y, accy);
            accx = fmaf(w2, f2.x, accx); accy = fmaf(w2, f2.y, accy);
            accx = fmaf(w3, f3.x, accx); accy = fmaf(w3, f3.y, accy);
        }
    }
    // cross-pair reduce: lanes q and q+32 hold partials of dims 2q,2q+1
    accx += __shfl_xor(accx, 32);
    accy += __shfl_xor(accy, 32);
    if (lane < 32) {
        float inv = 1.f / ssum;
        float2 o;
        o.x = accx * inv + bias[2 * q];
        o.y = accy * inv + bias[2 * q + 1];
        *reinterpret_cast<float2*>(&out[(size_t)node * DIM + 2 * q]) = o;
    }
}

extern "C" void kernel_launch(void* const* d_in, const int* in_sizes, int n_in,
                              void* d_out, int out_size, void* d_ws, size_t ws_size,
                              hipStream_t stream) {
    const float* x = (const float*)d_in[0];
    const int* ei = (const int*)d_in[1];   // harness converts integer inputs to int32
    const int n = out_size / DIM;          // 100000
    const int E = in_sizes[1] / 2;         // 1600000
    const int total_edges = E + n;
    const int NCB = (n + CBSZ - 1) >> CBSH;      // 196 coarse buckets (<=256)
    const int NPB = (E + CHUNK - 1) / CHUNK;     // 391 partition blocks (<=512)

    const float *W[3], *as_[3], *ad_[3], *b[3];
    for (int l = 0; l < 3; ++l) {
        W[l]  = (const float*)d_in[2 + 4 * l];
        as_[l] = (const float*)d_in[3 + 4 * l];
        ad_[l] = (const float*)d_in[4 + 4 * l];
        b[l]  = (const float*)d_in[5 + 4 * l];
    }

    // workspace carve (256B aligned). Inter-layer activations live in d_out.
    char* ws = (char*)d_ws;
    size_t off = 0;
    auto alloc = [&](size_t bytes) {
        void* p = ws + off;
        off = (off + bytes + 255) & ~(size_t)255;
        return p;
    };
    int* deg      = (int*)alloc((size_t)n * 4);
    int* row_ptr  = (int*)alloc((size_t)(n + 1) * 4);
    int* bsum     = (int*)alloc(512 * 4);
    int* hist2d   = (int*)alloc((size_t)NCB * NPB * 4);
    int* csr      = (int*)alloc((size_t)total_edges * 4);
    int2* part    = (int2*)alloc((size_t)E * 8);
    __half* h     = (__half*)alloc((size_t)n * DIM * 2);
    float* als    = (float*)alloc((size_t)n * 4);
    float* ald    = (float*)alloc((size_t)n * 4);
    float* buf    = (float*)d_out;         // inter-layer activations

    const int nbn = (n + 255) / 256;       // 391 (<=512 for scan_partials)

    // ---- CSR build (once; shared by all 3 layers) ----
    hipMemsetAsync(deg, 0, (size_t)n * 4, stream);
    k_part_hist<<<NPB, 256, 0, stream>>>(ei, deg, hist2d, E, NPB, NCB);
    k_scan_block<<<nbn, 256, 0, stream>>>(deg, row_ptr, bsum, n);
    k_scan_partials<<<1, 512, 0, stream>>>(bsum, nbn);
    k_scan_finish<<<nbn, 256, 0, stream>>>(row_ptr, bsum, n, total_edges);
    k_part_scan<<<NCB, 512, 0, stream>>>(row_ptr, hist2d, NPB);
    k_part_scatter<<<NPB, 256, 0, stream>>>(ei, hist2d, part, E, NPB, NCB);
    k_bucket_scatter<<<NCB, 256, 0, stream>>>(row_ptr, part, csr, n);

    // ---- 3 GAT layers ----
    const int aggr_blocks = (n + 3) / 4;   // 4 waves (nodes) per 256-thread block
    const int gemm_blocks = (n + 63) / 64;
    const float* xin = x;
    for (int l = 0; l < 3; ++l) {
        if (l == 0) {
            k_gemm_al<128><<<gemm_blocks, 256, 0, stream>>>(
                xin, 0, W[l], as_[l], ad_[l], h, als, ald, n);
        } else {
            k_gemm_al<64><<<gemm_blocks, 256, 0, stream>>>(
                xin, 1, W[l], as_[l], ad_[l], h, als, ald, n);
        }
        float* dst = (l == 2) ? (float*)d_out : buf;
        k_node_aggr<<<aggr_blocks, 256, 0, stream>>>(row_ptr, csr, als, ald, h, b[l], dst, n);
        xin = buf;
    }
}

// Round 12
// 277.559 us; speedup vs baseline: 1.4329x; 1.2190x over previous
//
#include <hip/hip_runtime.h>
#include <hip/hip_fp16.h>
#include <math.h>

#define DIM 64
#define CBSH 9                 // coarse bucket: 512 dst nodes
#define CBSZ (1 << CBSH)
#define CHUNK 4096             // edges per partition block

__device__ __forceinline__ float leaky(float e) { return e > 0.f ? e : 0.2f * e; }

// ---------------- CSR build (no global per-node atomics anywhere) ----------------
// P1: per-block LDS histogram over coarse buckets.
__global__ __launch_bounds__(256) void k_part_hist(
        const int* __restrict__ ei, int* __restrict__ hist2d,
        int E, int NPB, int NCB) {
    __shared__ int hist[256];
    int blk = blockIdx.x;
    int base = blk * CHUNK;
    int ecnt = min(CHUNK, E - base);
    for (int i = threadIdx.x; i < 256; i += 256) hist[i] = 0;
    __syncthreads();
    for (int i = threadIdx.x; i < ecnt; i += 256)
        atomicAdd(&hist[ei[E + base + i] >> CBSH], 1);
    __syncthreads();
    for (int cb = threadIdx.x; cb < NCB; cb += 256)
        hist2d[cb * NPB + blk] = hist[cb];
}

// P2: per coarse bucket, relative exclusive scan of per-block counts + total.
__global__ __launch_bounds__(512) void k_part_scan(
        int* __restrict__ hist2d, int* __restrict__ btot, int NPB) {
    __shared__ int tmp[512];
    int cb = blockIdx.x;
    int t = threadIdx.x;
    int v = (t < NPB) ? hist2d[cb * NPB + t] : 0;
    tmp[t] = v;
    __syncthreads();
    for (int off = 1; off < 512; off <<= 1) {
        int u = (t >= off) ? tmp[t - off] : 0;
        __syncthreads();
        tmp[t] += u;
        __syncthreads();
    }
    if (t < NPB) hist2d[cb * NPB + t] = tmp[t] - v;   // relative exclusive
    if (t == NPB - 1) btot[cb] = tmp[t];              // bucket edge total
}

// P2b: exclusive scan of bucket totals -> bucket edge bases. Also row_ptr[n].
__global__ __launch_bounds__(256) void k_ebase(
        const int* __restrict__ btot, int* __restrict__ ebase,
        int* __restrict__ row_ptr, int NCB, int n, int E) {
    __shared__ int tmp[256];
    int t = threadIdx.x;
    int v = (t < NCB) ? btot[t] : 0;
    tmp[t] = v;
    __syncthreads();
    for (int off = 1; off < 256; off <<= 1) {
        int u = (t >= off) ? tmp[t - off] : 0;
        __syncthreads();
        tmp[t] += u;
        __syncthreads();
    }
    if (t < NCB) ebase[t] = tmp[t] - v;
    if (t == NCB - 1) ebase[NCB] = tmp[t];   // == E
    if (t == 0) row_ptr[n] = E + n;
}

// P3: write edges into this block's private contiguous runs, packed 4B:
// (s << CBSH) | (d & (CBSZ-1)).  s < 2^17, local d < 2^9 -> 26 bits.
__global__ __launch_bounds__(256) void k_part_scatter(
        const int* __restrict__ ei, const int* __restrict__ hist2d,
        const int* __restrict__ ebase, int* __restrict__ part,
        int E, int NPB, int NCB) {
    __shared__ int gb[256];
    __shared__ int cnt[256];
    int blk = blockIdx.x;
    int base = blk * CHUNK;
    int ecnt = min(CHUNK, E - base);
    for (int i = threadIdx.x; i < NCB; i += 256) {
        gb[i] = ebase[i] + hist2d[i * NPB + blk];
        cnt[i] = 0;
    }
    __syncthreads();
    for (int i = threadIdx.x; i < ecnt; i += 256) {
        int s = ei[base + i];
        int d = ei[E + base + i];
        int cb = d >> CBSH;
        int off = atomicAdd(&cnt[cb], 1);  // LDS ticket within run
        part[gb[cb] + off] = (s << CBSH) | (d & (CBSZ - 1));
    }
}

// P4: one block per bucket. LDS degree count -> LDS scan -> row_ptr slice,
// self loops, and edge scatter via LDS cursors. No global atomics.
__global__ __launch_bounds__(256) void k_bucket_scatter(
        const int* __restrict__ ebase, const int* __restrict__ part,
        int* __restrict__ row_ptr, int* __restrict__ csr, int n) {
    __shared__ int arr[CBSZ];
    __shared__ int lcur[CBSZ];
    int cb = blockIdx.x;
    int d0 = cb << CBSH;
    int nb = min(CBSZ, n - d0);
    int t = threadIdx.x;
    int ebeg = ebase[cb], eend = ebase[cb + 1];
    arr[t] = 0; arr[t + 256] = 0;
    __syncthreads();
    for (int p = ebeg + t; p < eend; p += 256)
        atomicAdd(&arr[part[p] & (CBSZ - 1)], 1);
    __syncthreads();
    // v = deg + 1 (self loop) for valid nodes
    int v0 = (t < nb) ? arr[t] + 1 : 0;
    int v1 = (t + 256 < nb) ? arr[t + 256] + 1 : 0;
    __syncthreads();
    arr[t] = v0; arr[t + 256] = v1;
    __syncthreads();
    // inclusive Hillis-Steele scan over 512 entries
    for (int off = 1; off < 512; off <<= 1) {
        int a0 = (t >= off) ? arr[t - off] : 0;
        int a1 = (t + 256 >= off) ? arr[t + 256 - off] : 0;
        __syncthreads();
        arr[t] += a0; arr[t + 256] += a1;
        __syncthreads();
    }
    int nbase = ebeg + d0;   // csr slots before this bucket = edges + self loops
    if (t < nb) {
        int rp = nbase + arr[t] - v0;
        row_ptr[d0 + t] = rp;
        csr[rp] = d0 + t;          // self loop at slot 0
        lcur[t] = rp + 1;
    }
    if (t + 256 < nb) {
        int rp = nbase + arr[t + 256] - v1;
        row_ptr[d0 + t + 256] = rp;
        csr[rp] = d0 + t + 256;
        lcur[t + 256] = rp + 1;
    }
    __syncthreads();
    for (int p = ebeg + t; p < eend; p += 256) {
        int v = part[p];
        int slot = atomicAdd(&lcur[v & (CBSZ - 1)], 1);
        csr[slot] = v >> CBSH;
    }
}

// ---------------- per-layer: K-tiled LDS GEMM + attention projections ----------------
// h stored as fp16 (message payload only; als/ald/softmax stay fp32).
template <int FIN>
__global__ __launch_bounds__(256, 4) void k_gemm_al(
        const float* __restrict__ x, int do_relu,
        const float* __restrict__ W,
        const float* __restrict__ as_, const float* __restrict__ ad_,
        __half* __restrict__ h, float* __restrict__ als, float* __restrict__ ald,
        int n) {
    constexpr int KT = 64;
    constexpr int BM = 64;
    __shared__ float ws[KT * 64];        // [k][col]
    __shared__ float xs[BM * (KT + 1)];  // [row][k], stride 65

    const int tid = threadIdx.x;
    const int row0 = blockIdx.x * BM;
    const int rt = tid >> 4, ct = tid & 15;
    const int r0 = rt * 4, c0 = ct * 4;

    float acc[4][4];
#pragma unroll
    for (int i = 0; i < 4; ++i)
#pragma unroll
        for (int j = 0; j < 4; ++j) acc[i][j] = 0.f;

    for (int kt = 0; kt < FIN; kt += KT) {
#pragma unroll
        for (int p = 0; p < KT * 16 / 256; ++p) {
            int i = tid + p * 256;
            *reinterpret_cast<float4*>(&ws[i * 4]) =
                *reinterpret_cast<const float4*>(&W[kt * 64 + i * 4]);
        }
#pragma unroll
        for (int p = 0; p < BM * (KT / 4) / 256; ++p) {
            int i = tid + p * 256;
            int r = i >> 4;          // 16 quads per row
            int kq = i & 15;
            int grow = row0 + r;
            float4 v = make_float4(0.f, 0.f, 0.f, 0.f);
            if (grow < n)
                v = *reinterpret_cast<const float4*>(&x[(size_t)grow * FIN + kt + kq * 4]);
            if (do_relu) {
                v.x = fmaxf(v.x, 0.f); v.y = fmaxf(v.y, 0.f);
                v.z = fmaxf(v.z, 0.f); v.w = fmaxf(v.w, 0.f);
            }
            float* dst = &xs[r * (KT + 1) + kq * 4];
            dst[0] = v.x; dst[1] = v.y; dst[2] = v.z; dst[3] = v.w;
        }
        __syncthreads();

#pragma unroll 4
        for (int k = 0; k < KT; ++k) {
            float4 wv = *reinterpret_cast<const float4*>(&ws[k * 64 + c0]);
            float xv0 = xs[(r0 + 0) * (KT + 1) + k];
            float xv1 = xs[(r0 + 1) * (KT + 1) + k];
            float xv2 = xs[(r0 + 2) * (KT + 1) + k];
            float xv3 = xs[(r0 + 3) * (KT + 1) + k];
            acc[0][0] = fmaf(xv0, wv.x, acc[0][0]);
            acc[0][1] = fmaf(xv0, wv.y, acc[0][1]);
            acc[0][2] = fmaf(xv0, wv.z, acc[0][2]);
            acc[0][3] = fmaf(xv0, wv.w, acc[0][3]);
            acc[1][0] = fmaf(xv1, wv.x, acc[1][0]);
            acc[1][1] = fmaf(xv1, wv.y, acc[1][1]);
            acc[1][2] = fmaf(xv1, wv.z, acc[1][2]);
            acc[1][3] = fmaf(xv1, wv.w, acc[1][3]);
            acc[2][0] = fmaf(xv2, wv.x, acc[2][0]);
            acc[2][1] = fmaf(xv2, wv.y, acc[2][1]);
            acc[2][2] = fmaf(xv2, wv.z, acc[2][2]);
            acc[2][3] = fmaf(xv2, wv.w, acc[2][3]);
            acc[3][0] = fmaf(xv3, wv.x, acc[3][0]);
            acc[3][1] = fmaf(xv3, wv.y, acc[3][1]);
            acc[3][2] = fmaf(xv3, wv.z, acc[3][2]);
            acc[3][3] = fmaf(xv3, wv.w, acc[3][3]);
        }
        __syncthreads();
    }

    float4 asv = *reinterpret_cast<const float4*>(&as_[c0]);
    float4 adv = *reinterpret_cast<const float4*>(&ad_[c0]);
#pragma unroll
    for (int i = 0; i < 4; ++i) {
        int grow = row0 + r0 + i;
        if (grow < n) {
            __half2 p0 = __floats2half2_rn(acc[i][0], acc[i][1]);
            __half2 p1 = __floats2half2_rn(acc[i][2], acc[i][3]);
            uint2 pk = make_uint2(*reinterpret_cast<unsigned*>(&p0),
                                  *reinterpret_cast<unsigned*>(&p1));
            *reinterpret_cast<uint2*>(&h[(size_t)grow * 64 + c0]) = pk;  // 8B aligned
        }
        float ps = acc[i][0] * asv.x + acc[i][1] * asv.y +
                   acc[i][2] * asv.z + acc[i][3] * asv.w;
        float pd = acc[i][0] * adv.x + acc[i][1] * adv.y +
                   acc[i][2] * adv.z + acc[i][3] * adv.w;
#pragma unroll
        for (int off = 1; off < 16; off <<= 1) {
            ps += __shfl_xor(ps, off);
            pd += __shfl_xor(pd, off);
        }
        if (ct == 0 && grow < n) { als[grow] = ps; ald[grow] = pd; }
    }
}

// ---------------- per-layer: fused logits + exact softmax + aggregation ----------------
__global__ __launch_bounds__(256) void k_node_aggr(
        const int* __restrict__ row_ptr, const int* __restrict__ csr,
        const float* __restrict__ als, const float* __restrict__ ald,
        const __half* __restrict__ h, const float* __restrict__ bias,
        float* __restrict__ out, int n) {
    int wid = threadIdx.x >> 6, lane = threadIdx.x & 63;
    int node = blockIdx.x * 4 + wid;
    if (node >= n) return;
    int beg = row_ptr[node];
    int deg = row_ptr[node + 1] - beg;
    float adv = ald[node];
    const int g = lane >> 5;   // row within pair
    const int q = lane & 31;   // dim-pair index (dims 2q, 2q+1)
    float m = -INFINITY, ssum = 0.f;
    float accx = 0.f, accy = 0.f;
    for (int c0 = 0; c0 < deg; c0 += 64) {
        int cn = min(64, deg - c0);
        int s_l = 0;
        float e_l = -INFINITY;
        if (lane < cn) {
            s_l = csr[beg + c0 + lane];
            e_l = leaky(als[s_l] + adv);
        }
        // chunk max
        float cm = e_l;
#pragma unroll
        for (int off = 32; off; off >>= 1) cm = fmaxf(cm, __shfl_xor(cm, off));
        float mnew = fmaxf(m, cm);
        float sc = __expf(m - mnew);   // first chunk: exp(-inf)=0
        // lane-parallel weights: ONE exp per edge; w=0 (s=0) for pad lanes
        float w_l = (lane < cn) ? __expf(e_l - mnew) : 0.f;
        float cs = w_l;
#pragma unroll
        for (int off = 32; off; off >>= 1) cs += __shfl_xor(cs, off);
        ssum = ssum * sc + cs;
        accx *= sc; accy *= sc;
        m = mnew;
        // gather: 8 rows per iteration (4 substeps x 2 rows). Pad lanes w=0.
        int cn8 = (cn + 7) & ~7;
        for (int j = 0; j < cn8; j += 8) {
            int   s0 = __shfl(s_l, j + g),     s1 = __shfl(s_l, j + 2 + g);
            int   s2 = __shfl(s_l, j + 4 + g), s3 = __shfl(s_l, j + 6 + g);
            float w0 = __shfl(w_l, j + g),     w1 = __shfl(w_l, j + 2 + g);
            float w2 = __shfl(w_l, j + 4 + g), w3 = __shfl(w_l, j + 6 + g);
            __half2 a0 = *reinterpret_cast<const __half2*>(&h[(size_t)s0 * DIM + 2 * q]);
            __half2 a1 = *reinterpret_cast<const __half2*>(&h[(size_t)s1 * DIM + 2 * q]);
            __half2 a2 = *reinterpret_cast<const __half2*>(&h[(size_t)s2 * DIM + 2 * q]);
            __half2 a3 = *reinterpret_cast<const __half2*>(&h[(size_t)s3 * DIM + 2 * q]);
            float2 f0 = __half22float2(a0);
            float2 f1 = __half22float2(a1);
            float2 f2 = __half22float2(a2);
            float2 f3 = __half22float2(a3);
            accx = fmaf(w0, f0.x, accx); accy = fmaf(w0, f0.y, accy);
            accx = fmaf(w1, f1.x, accx); accy = fmaf(w1, f1.y, accy);
            accx = fmaf(w2, f2.x, accx); accy = fmaf(w2, f2.y, accy);
            accx = fmaf(w3, f3.x, accx); accy = fmaf(w3, f3.y, accy);
        }
    }
    // cross-pair reduce: lanes q and q+32 hold partials of dims 2q,2q+1
    accx += __shfl_xor(accx, 32);
    accy += __shfl_xor(accy, 32);
    if (lane < 32) {
        float inv = 1.f / ssum;
        float2 o;
        o.x = accx * inv + bias[2 * q];
        o.y = accy * inv + bias[2 * q + 1];
        *reinterpret_cast<float2*>(&out[(size_t)node * DIM + 2 * q]) = o;
    }
}

extern "C" void kernel_launch(void* const* d_in, const int* in_sizes, int n_in,
                              void* d_out, int out_size, void* d_ws, size_t ws_size,
                              hipStream_t stream) {
    const float* x = (const float*)d_in[0];
    const int* ei = (const int*)d_in[1];   // harness converts integer inputs to int32
    const int n = out_size / DIM;          // 100000
    const int E = in_sizes[1] / 2;         // 1600000
    const int total_edges = E + n;
    const int NCB = (n + CBSZ - 1) >> CBSH;      // 196 coarse buckets (<=256)
    const int NPB = (E + CHUNK - 1) / CHUNK;     // 391 partition blocks (<=512)

    const float *W[3], *as_[3], *ad_[3], *b[3];
    for (int l = 0; l < 3; ++l) {
        W[l]  = (const float*)d_in[2 + 4 * l];
        as_[l] = (const float*)d_in[3 + 4 * l];
        ad_[l] = (const float*)d_in[4 + 4 * l];
        b[l]  = (const float*)d_in[5 + 4 * l];
    }

    // workspace carve (256B aligned). Inter-layer activations live in d_out.
    char* ws = (char*)d_ws;
    size_t off = 0;
    auto alloc = [&](size_t bytes) {
        void* p = ws + off;
        off = (off + bytes + 255) & ~(size_t)255;
        return p;
    };
    int* row_ptr  = (int*)alloc((size_t)(n + 1) * 4);
    int* hist2d   = (int*)alloc((size_t)NCB * NPB * 4);
    int* btot     = (int*)alloc(256 * 4);
    int* ebase    = (int*)alloc(257 * 4);
    int* csr      = (int*)alloc((size_t)total_edges * 4);
    int* part     = (int*)alloc((size_t)E * 4);
    __half* h     = (__half*)alloc((size_t)n * DIM * 2);
    float* als    = (float*)alloc((size_t)n * 4);
    float* ald    = (float*)alloc((size_t)n * 4);
    float* buf    = (float*)d_out;         // inter-layer activations

    // ---- CSR build (once; shared by all 3 layers) ----
    k_part_hist<<<NPB, 256, 0, stream>>>(ei, hist2d, E, NPB, NCB);
    k_part_scan<<<NCB, 512, 0, stream>>>(hist2d, btot, NPB);
    k_ebase<<<1, 256, 0, stream>>>(btot, ebase, row_ptr, NCB, n, E);
    k_part_scatter<<<NPB, 256, 0, stream>>>(ei, hist2d, ebase, part, E, NPB, NCB);
    k_bucket_scatter<<<NCB, 256, 0, stream>>>(ebase, part, row_ptr, csr, n);

    // ---- 3 GAT layers ----
    const int aggr_blocks = (n + 3) / 4;   // 4 waves (nodes) per 256-thread block
    const int gemm_blocks = (n + 63) / 64;
    const float* xin = x;
    for (int l = 0; l < 3; ++l) {
        if (l == 0) {
            k_gemm_al<128><<<gemm_blocks, 256, 0, stream>>>(
                xin, 0, W[l], as_[l], ad_[l], h, als, ald, n);
        } else {
            k_gemm_al<64><<<gemm_blocks, 256, 0, stream>>>(
                xin, 1, W[l], as_[l], ad_[l], h, als, ald, n);
        }
        float* dst = (l == 2) ? (float*)d_out : buf;
        k_node_aggr<<<aggr_blocks, 256, 0, stream>>>(row_ptr, csr, als, ald, h, b[l], dst, n);
        xin = buf;
    }
}